// Round 13
// baseline (689.794 us; speedup 1.0000x reference)
//
#include <hip/hip_runtime.h>
#include <hip/hip_bf16.h>

// ---------------------------------------------------------------------------
// HazardGNN round 15: r11 kernel (best verified, reproduced 667.9/671.6 us)
// with ONE zero-risk change: edge/head grid 512 -> 1024. Grid 512 = exactly
// 2 blocks/CU with an empty queue; 6250 chunks / 512 blocks = 12.2 chunks each
// with variable per-chunk cost (segment counts, atomic contention) -> tail
// imbalance. Grid 1024 halves per-block work and lets the dispatcher backfill
// early-finishing CUs. Kernel bodies byte-identical to r11.
// ---------------------------------------------------------------------------

typedef __attribute__((ext_vector_type(8))) short bf16x8;
typedef __attribute__((ext_vector_type(4))) float f32x4;
#define MFMA16(a, b, c) __builtin_amdgcn_mfma_f32_16x16x32_bf16(a, b, c, 0, 0, 0)

#define CHUNK 128
#define XSTRIDE 336   // bytes per x row: 168 bf16 (K padded to 160, +8 slack)
#define MSTRIDE 264   // bytes per m row: 66 f32
#define HSTRIDE 144   // bytes per hid row: 72 bf16
#define SLABSZ 10752  // 32 * XSTRIDE
#define HIDSZ  4608   // 32 * HSTRIDE

// GRU LDS strides (+8 bf16 pad to break power-of-2 banking)
#define WRZST 264     // 128 bf16 + 4 pad
#define WNST  136     // 64 bf16 + 4 pad

__device__ __forceinline__ float fast_sig(float x) { return 1.f / (1.f + __expf(-x)); }
__device__ __forceinline__ float fast_tanh(float x) {
    float ax = fabsf(x);
    float t = __expf(-2.f * ax);
    return copysignf((1.f - t) / (1.f + t), x);
}
__device__ __forceinline__ ushort f2bf(float f) {  // RNE fp32->bf16
    unsigned u = __float_as_uint(f);
    unsigned r = u + 0x7FFF + ((u >> 16) & 1);
    return (ushort)(r >> 16);
}
__device__ __forceinline__ float bf2f(ushort b) {
    return __uint_as_float(((unsigned)b) << 16);
}
__device__ __forceinline__ unsigned pkbf2(float a, float b) {  // 2xf32 -> packed bf16 (RNE)
    unsigned r;
    asm("v_cvt_pk_bf16_f32 %0, %1, %2" : "=v"(r) : "v"(a), "v"(b));
    return r;
}

// ---------------------------------------------------------------------------
// prep: bf16 weight images. W1 images carry the layer bias in two
// ones-columns: k=132 -> bf16(b), k=133 -> bf16(b - fp32(bf16(b))).
// ---------------------------------------------------------------------------
__global__ void prep_kernel(const float* __restrict__ msg_w1,
                            const float* __restrict__ msg_b1,
                            const float* __restrict__ msg_w2,
                            const float* __restrict__ gru_wih,
                            const float* __restrict__ gru_whh,
                            const float* __restrict__ head_w1,
                            const float* __restrict__ head_b1,
                            const float* __restrict__ head_w2,
                            ushort* __restrict__ Wb1, ushort* __restrict__ Wb2,
                            ushort* __restrict__ Wh1, ushort* __restrict__ Wh2b,
                            ushort* __restrict__ Wrz, ushort* __restrict__ Wni,
                            ushort* __restrict__ Wnh) {
    int t = blockIdx.x * 256 + threadIdx.x;
    if (t < 30720) {  // Wb1[l][j][k<160]
        int l = t / 10240, r = t % 10240, j = r / 160, k = r % 160;
        float v = 0.f;
        if (k < 132) {
            v = msg_w1[l * 8448 + j * 132 + k];
        } else if (k == 132) {
            v = msg_b1[l * 64 + j];
        } else if (k == 133) {
            float b = msg_b1[l * 64 + j];
            v = b - bf2f(f2bf(b));
        }
        Wb1[t] = f2bf(v);
        return;
    }
    t -= 30720;
    if (t < 12288) {  // Wb2[l][j][k<64]
        Wb2[t] = f2bf(msg_w2[t]);
        return;
    }
    t -= 12288;
    if (t < 10240) {  // Wh1[j][k<160]
        int j = t / 160, k = t % 160;
        float v = 0.f;
        if (k < 132) {
            v = head_w1[j * 132 + k];
        } else if (k == 132) {
            v = head_b1[j];
        } else if (k == 133) {
            float b = head_b1[j];
            v = b - bf2f(f2bf(b));
        }
        Wh1[t] = f2bf(v);
        return;
    }
    t -= 10240;
    if (t < 1024) {  // Wh2b[16][64]: row 0 = head_w2, rows 1..15 zero
        int j = t >> 6, k = t & 63;
        Wh2b[t] = (j == 0) ? f2bf(head_w2[k]) : 0;
        return;
    }
    t -= 1024;
    if (t < 49152) {  // Wrz[l][n][k]
        int l = t / 16384, r = t % 16384, n = r >> 7, k = r & 127;
        float v = (k < 64) ? gru_wih[l * 12288 + n * 64 + k]
                           : gru_whh[l * 12288 + n * 64 + (k - 64)];
        Wrz[t] = f2bf(v);
        return;
    }
    t -= 49152;
    if (t < 12288) {  // Wni[l][j][k]
        int l = t / 4096, r = t % 4096, j = r >> 6, k = r & 63;
        Wni[t] = f2bf(gru_wih[l * 12288 + (128 + j) * 64 + k]);
        return;
    }
    t -= 12288;
    if (t < 12288) {  // Wnh[l][j][k]
        int l = t / 4096, r = t % 4096, j = r >> 6, k = r & 63;
        Wnh[t] = f2bf(gru_whh[l * 12288 + (128 + j) * 64 + k]);
    }
}

// h (fp32) + hb (bf16 mirror) from embedding
__global__ void embed_kernel(float* __restrict__ h, ushort* __restrict__ hb,
                             const float* __restrict__ emb,
                             const int* __restrict__ kinds, int N) {
    int t = blockIdx.x * 256 + threadIdx.x;
    if (t >= N * 64) return;
    int node = t >> 6, d = t & 63;
    float v = emb[kinds[node] * 64 + d];
    h[t] = v;
    hb[t] = f2bf(v);
}

// -------------------- counting sort by dst --------------------
__global__ void hist_kernel(const int* __restrict__ dst, int* __restrict__ deg, int E) {
    int e = blockIdx.x * 256 + threadIdx.x;
    if (e < E) atomicAdd(&deg[dst[e]], 1);
}

__global__ void scan_kernel(const int* __restrict__ deg, int* __restrict__ cursor, int N) {
    __shared__ int sums[1024];
    int tid = threadIdx.x;
    int chunk = (N + 1023) >> 10;
    int lo = tid * chunk, hi = min(lo + chunk, N);
    int s = 0;
    for (int i = lo; i < hi; i++) s += deg[i];
    sums[tid] = s;
    __syncthreads();
    for (int off = 1; off < 1024; off <<= 1) {
        int v = (tid >= off) ? sums[tid - off] : 0;
        __syncthreads();
        sums[tid] += v;
        __syncthreads();
    }
    int run = (tid > 0) ? sums[tid - 1] : 0;
    for (int i = lo; i < hi; i++) {
        cursor[i] = run;
        run += deg[i];
    }
}

__global__ void scatter_kernel(const int* __restrict__ src, const int* __restrict__ dst,
                               const float* __restrict__ ea, int* __restrict__ cursor,
                               int* __restrict__ src_s, int* __restrict__ dst_s,
                               ushort* __restrict__ ea_sb, int E) {
    int e = blockIdx.x * 256 + threadIdx.x;
    if (e >= E) return;
    int d = dst[e];
    int p = atomicAdd(&cursor[d], 1);
    src_s[p] = src[e];
    dst_s[p] = d;
    float4 e4 = ((const float4*)ea)[e];
    ushort4 eb;
    eb.x = f2bf(e4.x); eb.y = f2bf(e4.y); eb.z = f2bf(e4.z); eb.w = f2bf(e4.w);
    ((ushort4*)ea_sb)[p] = eb;
}

// ---------------------------------------------------------------------------
// edge message kernel: r4 slab structure, GEMM1 swapped + cvt_pk epilogue.
// ---------------------------------------------------------------------------
__global__ __launch_bounds__(256) void edge_msg_mfma(
    const ushort* __restrict__ hb, const int* __restrict__ src_s,
    const int* __restrict__ dst_s, const ushort* __restrict__ ea_sb,
    const ushort* __restrict__ Wb1l, const ushort* __restrict__ Wb2l,
    const float* __restrict__ b2,
    float* __restrict__ agg, int E, int nchunks) {
    __shared__ char lds[4 * SLABSZ + 4 * HIDSZ];  // 61440 B
    int tid = threadIdx.x;
    int w = tid >> 6, lane = tid & 63;
    int quad = lane >> 4, nrow = lane & 15;
    char* slab = lds + w * SLABSZ;
    char* hidb = lds + 4 * SLABSZ + w * HIDSZ;

    bf16x8 wf1[4][5], wf2[4][2];
    float b2v[4];
#pragma unroll
    for (int nt = 0; nt < 4; nt++) {
        int n = nt * 16 + nrow;
#pragma unroll
        for (int ks = 0; ks < 5; ks++)
            wf1[nt][ks] = *(const bf16x8*)(Wb1l + n * 160 + ks * 32 + quad * 8);
#pragma unroll
        for (int ks = 0; ks < 2; ks++)
            wf2[nt][ks] = *(const bf16x8*)(Wb2l + n * 64 + ks * 32 + quad * 8);
        b2v[nt] = b2[n];
    }

    for (int chunk = blockIdx.x; chunk < nchunks; chunk += gridDim.x) {
        int ebase = chunk * CHUNK;
        {
            int el = tid >> 1, half = tid & 1;
            int r = el & 31;
            int ec = min(ebase + el, E - 1);
            int node = half ? dst_s[ec] : src_s[ec];
            const float4* hrow = (const float4*)(hb + (size_t)node * 64);
            float4* xw = (float4*)(slab + r * XSTRIDE + half * 128);
#pragma unroll
            for (int i = 0; i < 8; i++) xw[i] = hrow[i];
            if (half == 0) {
                *(uint2*)(slab + r * XSTRIDE + 256) = *(const uint2*)(ea_sb + (size_t)ec * 4);
            } else {
                // k=132,133 = 1.0 (bias ones-columns); k=134.. zero
                uint2 ones2 = {0x3F803F80u, 0u};
                float4 z4 = {0.f, 0.f, 0.f, 0.f};
                *(uint2*)(slab + r * XSTRIDE + 264) = ones2;
                *(float4*)(slab + r * XSTRIDE + 272) = z4;
                *(float4*)(slab + r * XSTRIDE + 288) = z4;
                *(float4*)(slab + r * XSTRIDE + 304) = z4;
            }
        }
        // GEMM1 (swapped): acc1[nt][et], C row = n (nt*16+quad*4+rg),
        // col = edge (et*16+nrow). Bias comes from the ones-columns.
        f32x4 acc1[4][2];
#pragma unroll
        for (int nt = 0; nt < 4; nt++) {
            f32x4 z4;
            z4[0] = z4[1] = z4[2] = z4[3] = 0.f;
            acc1[nt][0] = z4;
            acc1[nt][1] = z4;
        }
#pragma unroll
        for (int ks = 0; ks < 5; ks++) {
            bf16x8 xb0 = *(const bf16x8*)(slab + nrow * XSTRIDE + ks * 64 + quad * 16);
            bf16x8 xb1 = *(const bf16x8*)(slab + (16 + nrow) * XSTRIDE + ks * 64 + quad * 16);
#pragma unroll
            for (int nt = 0; nt < 4; nt++) {
                acc1[nt][0] = MFMA16(wf1[nt][ks], xb0, acc1[nt][0]);
                acc1[nt][1] = MFMA16(wf1[nt][ks], xb1, acc1[nt][1]);
            }
        }
        // silu -> packed bf16 -> hid[edge][n] (8B stores, HSTRIDE breaks banks)
#pragma unroll
        for (int nt = 0; nt < 4; nt++)
#pragma unroll
            for (int et = 0; et < 2; et++) {
                f32x4 a = acc1[nt][et];
                float v0 = a[0] * fast_sig(a[0]);
                float v1 = a[1] * fast_sig(a[1]);
                float v2 = a[2] * fast_sig(a[2]);
                float v3 = a[3] * fast_sig(a[3]);
                int er = et * 16 + nrow;
                uint2 pk;
                pk.x = pkbf2(v0, v1);
                pk.y = pkbf2(v2, v3);
                *(uint2*)(hidb + er * HSTRIDE + nt * 32 + quad * 8) = pk;
            }
        // GEMM2 (unswapped): C[edge][n2]
        f32x4 acc2[2][4];
#pragma unroll
        for (int mt = 0; mt < 2; mt++)
#pragma unroll
            for (int nt = 0; nt < 4; nt++) {
                f32x4 v;
                v[0] = v[1] = v[2] = v[3] = b2v[nt];
                acc2[mt][nt] = v;
            }
#pragma unroll
        for (int ks = 0; ks < 2; ks++) {
            bf16x8 a0 = *(const bf16x8*)(hidb + nrow * HSTRIDE + ks * 64 + quad * 16);
            bf16x8 a1 = *(const bf16x8*)(hidb + (16 + nrow) * HSTRIDE + ks * 64 + quad * 16);
#pragma unroll
            for (int nt = 0; nt < 4; nt++) {
                acc2[0][nt] = MFMA16(a0, wf2[nt][ks], acc2[0][nt]);
                acc2[1][nt] = MFMA16(a1, wf2[nt][ks], acc2[1][nt]);
            }
        }
#pragma unroll
        for (int mt = 0; mt < 2; mt++)
#pragma unroll
            for (int nt = 0; nt < 4; nt++)
#pragma unroll
                for (int rg = 0; rg < 4; rg++) {
                    int rm = mt * 16 + quad * 4 + rg;
                    *(float*)(slab + rm * MSTRIDE + (nt * 16 + nrow) * 4) = acc2[mt][nt][rg];
                }
        {
            int e32 = ebase + w * 32;
            int dmy = dst_s[min(e32 + (lane & 31), E - 1)];
            int limit = min(32, E - e32);
            int nx = __shfl_down(dmy, 1);
            bool tl = ((lane & 31) == 31) || (dmy != nx);
            unsigned long long tm = __ballot(tl);
            float run = 0.f;
#pragma unroll
            for (int i = 0; i < 32; i++) {
                if (i < limit) {
                    run += *(const float*)(slab + i * MSTRIDE + lane * 4);
                    if (((tm >> i) & 1ull) || (i + 1 == limit)) {
                        int di = __shfl(dmy, i);
                        unsafeAtomicAdd(&agg[(size_t)di * 64 + lane], run);
                        run = 0.f;
                    }
                }
            }
        }
    }
}

// ---------------------------------------------------------------------------
// head kernel: r4 slab structure, GEMM1 swapped + cvt_pk epilogue.
// ---------------------------------------------------------------------------
__global__ __launch_bounds__(256) void head_mfma(
    const ushort* __restrict__ hb, const int* __restrict__ src,
    const int* __restrict__ dst, const float* __restrict__ ea,
    const ushort* __restrict__ Wh1, const ushort* __restrict__ Wh2b,
    const float* __restrict__ hb2p,
    float* __restrict__ out, int E, int nchunks) {
    __shared__ char lds[4 * SLABSZ + 4 * HIDSZ];
    int tid = threadIdx.x;
    int w = tid >> 6, lane = tid & 63;
    int quad = lane >> 4, nrow = lane & 15;
    char* slab = lds + w * SLABSZ;
    char* hidb = lds + 4 * SLABSZ + w * HIDSZ;

    bf16x8 wf1[4][5], wh2[2];
#pragma unroll
    for (int nt = 0; nt < 4; nt++) {
        int n = nt * 16 + nrow;
#pragma unroll
        for (int ks = 0; ks < 5; ks++)
            wf1[nt][ks] = *(const bf16x8*)(Wh1 + n * 160 + ks * 32 + quad * 8);
    }
#pragma unroll
    for (int ks = 0; ks < 2; ks++)
        wh2[ks] = *(const bf16x8*)(Wh2b + nrow * 64 + ks * 32 + quad * 8);
    float hb2 = hb2p[0];

    for (int chunk = blockIdx.x; chunk < nchunks; chunk += gridDim.x) {
        int ebase = chunk * CHUNK;
        {
            int el = tid >> 1, half = tid & 1;
            int r = el & 31;
            int ec = min(ebase + el, E - 1);
            int node = half ? dst[ec] : src[ec];
            const float4* hrow = (const float4*)(hb + (size_t)node * 64);
            float4* xw = (float4*)(slab + r * XSTRIDE + half * 128);
#pragma unroll
            for (int i = 0; i < 8; i++) xw[i] = hrow[i];
            if (half == 0) {
                float4 e4 = ((const float4*)ea)[ec];
                ushort4 eb;
                eb.x = f2bf(e4.x); eb.y = f2bf(e4.y); eb.z = f2bf(e4.z); eb.w = f2bf(e4.w);
                *(ushort4*)(slab + r * XSTRIDE + 256) = eb;
            } else {
                uint2 ones2 = {0x3F803F80u, 0u};
                float4 z4 = {0.f, 0.f, 0.f, 0.f};
                *(uint2*)(slab + r * XSTRIDE + 264) = ones2;
                *(float4*)(slab + r * XSTRIDE + 272) = z4;
                *(float4*)(slab + r * XSTRIDE + 288) = z4;
                *(float4*)(slab + r * XSTRIDE + 304) = z4;
            }
        }
        f32x4 acc1[4][2];
#pragma unroll
        for (int nt = 0; nt < 4; nt++) {
            f32x4 z4;
            z4[0] = z4[1] = z4[2] = z4[3] = 0.f;
            acc1[nt][0] = z4;
            acc1[nt][1] = z4;
        }
#pragma unroll
        for (int ks = 0; ks < 5; ks++) {
            bf16x8 xb0 = *(const bf16x8*)(slab + nrow * XSTRIDE + ks * 64 + quad * 16);
            bf16x8 xb1 = *(const bf16x8*)(slab + (16 + nrow) * XSTRIDE + ks * 64 + quad * 16);
#pragma unroll
            for (int nt = 0; nt < 4; nt++) {
                acc1[nt][0] = MFMA16(wf1[nt][ks], xb0, acc1[nt][0]);
                acc1[nt][1] = MFMA16(wf1[nt][ks], xb1, acc1[nt][1]);
            }
        }
#pragma unroll
        for (int nt = 0; nt < 4; nt++)
#pragma unroll
            for (int et = 0; et < 2; et++) {
                f32x4 a = acc1[nt][et];
                float v0 = a[0] * fast_sig(a[0]);
                float v1 = a[1] * fast_sig(a[1]);
                float v2 = a[2] * fast_sig(a[2]);
                float v3 = a[3] * fast_sig(a[3]);
                int er = et * 16 + nrow;
                uint2 pk;
                pk.x = pkbf2(v0, v1);
                pk.y = pkbf2(v2, v3);
                *(uint2*)(hidb + er * HSTRIDE + nt * 32 + quad * 8) = pk;
            }
        f32x4 acc3[2];
#pragma unroll
        for (int mt = 0; mt < 2; mt++) {
            f32x4 v;
            v[0] = v[1] = v[2] = v[3] = 0.f;
            acc3[mt] = v;
        }
#pragma unroll
        for (int ks = 0; ks < 2; ks++) {
            bf16x8 a0 = *(const bf16x8*)(hidb + nrow * HSTRIDE + ks * 64 + quad * 16);
            bf16x8 a1 = *(const bf16x8*)(hidb + (16 + nrow) * HSTRIDE + ks * 64 + quad * 16);
            acc3[0] = MFMA16(a0, wh2[ks], acc3[0]);
            acc3[1] = MFMA16(a1, wh2[ks], acc3[1]);
        }
        if (nrow == 0) {
#pragma unroll
            for (int mt = 0; mt < 2; mt++)
#pragma unroll
                for (int rg = 0; rg < 4; rg++) {
                    int e = ebase + w * 32 + mt * 16 + quad * 4 + rg;
                    if (e < E) out[e] = fast_sig(acc3[mt][rg] + hb2);
                }
        }
    }
}

// ---------------------------------------------------------------------------
// GRU MFMA kernel (unchanged).
// ---------------------------------------------------------------------------
__device__ __forceinline__ bf16x8 aggfrag(const float* __restrict__ row, int off) {
    float4 f0 = *(const float4*)(row + off);
    float4 f1 = *(const float4*)(row + off + 4);
    bf16x8 r;
    r[0] = (short)f2bf(f0.x); r[1] = (short)f2bf(f0.y);
    r[2] = (short)f2bf(f0.z); r[3] = (short)f2bf(f0.w);
    r[4] = (short)f2bf(f1.x); r[5] = (short)f2bf(f1.y);
    r[6] = (short)f2bf(f1.z); r[7] = (short)f2bf(f1.w);
    return r;
}

__global__ __launch_bounds__(256) void gru_mfma(
    float* __restrict__ h, ushort* __restrict__ hb, const float* __restrict__ agg,
    const ushort* __restrict__ Wrzg, const ushort* __restrict__ Wnig,
    const ushort* __restrict__ Wnhg,
    const float* __restrict__ bih, const float* __restrict__ bhh, int N) {
    __shared__ char lds[128 * WRZST + 2 * 64 * WNST];  // 51200 B
    int tid = threadIdx.x, w = tid >> 6, lane = tid & 63;
    int quad = lane >> 4, nrow = lane & 15;
    char* wrz = lds;
    char* wni = lds + 128 * WRZST;
    char* wnh = wni + 64 * WNST;

    {
        int r = tid >> 1, half = tid & 1;
        const uint4* g = (const uint4*)(Wrzg + r * 128 + half * 64);
        uint4* d = (uint4*)(wrz + r * WRZST + half * 128);
#pragma unroll
        for (int i = 0; i < 8; i++) d[i] = g[i];
        if (tid < 128) {
            const uint4* g2 = (const uint4*)(Wnig + (tid >> 1) * 64 + (tid & 1) * 32);
            uint4* d2 = (uint4*)(wni + (tid >> 1) * WNST + (tid & 1) * 64);
#pragma unroll
            for (int i = 0; i < 4; i++) d2[i] = g2[i];
        } else {
            int t2 = tid - 128;
            const uint4* g2 = (const uint4*)(Wnhg + (t2 >> 1) * 64 + (t2 & 1) * 32);
            uint4* d2 = (uint4*)(wnh + (t2 >> 1) * WNST + (t2 & 1) * 64);
#pragma unroll
            for (int i = 0; i < 4; i++) d2[i] = g2[i];
        }
    }
    __syncthreads();

    int nb0 = blockIdx.x * 128 + w * 32;
    if (nb0 >= N) return;

    float brz[8], bi[4], bhv[4];
#pragma unroll
    for (int nt = 0; nt < 8; nt++) brz[nt] = bih[nt * 16 + nrow] + bhh[nt * 16 + nrow];
#pragma unroll
    for (int nt = 0; nt < 4; nt++) {
        bi[nt] = bih[128 + nt * 16 + nrow];
        bhv[nt] = bhh[128 + nt * 16 + nrow];
    }

    int n0 = min(nb0 + nrow, N - 1);
    int n1 = min(nb0 + 16 + nrow, N - 1);
    const float* ag0 = agg + (size_t)n0 * 64;
    const float* ag1 = agg + (size_t)n1 * 64;
    const ushort* hb0 = hb + (size_t)n0 * 64;
    const ushort* hb1 = hb + (size_t)n1 * 64;

    f32x4 accrz[2][8], acci[2][4], acch[2][4];
#pragma unroll
    for (int nt = 0; nt < 8; nt++) {
        f32x4 v; v[0] = v[1] = v[2] = v[3] = brz[nt];
        accrz[0][nt] = v; accrz[1][nt] = v;
    }
#pragma unroll
    for (int nt = 0; nt < 4; nt++) {
        f32x4 vi; vi[0] = vi[1] = vi[2] = vi[3] = bi[nt];
        acci[0][nt] = vi; acci[1][nt] = vi;
        f32x4 vh; vh[0] = vh[1] = vh[2] = vh[3] = bhv[nt];
        acch[0][nt] = vh; acch[1][nt] = vh;
    }

#pragma unroll
    for (int ks = 0; ks < 4; ks++) {
        bf16x8 a0, a1;
        if (ks < 2) {
            a0 = aggfrag(ag0, ks * 32 + quad * 8);
            a1 = aggfrag(ag1, ks * 32 + quad * 8);
        } else {
            a0 = *(const bf16x8*)(hb0 + (ks - 2) * 32 + quad * 8);
            a1 = *(const bf16x8*)(hb1 + (ks - 2) * 32 + quad * 8);
        }
#pragma unroll
        for (int nt = 0; nt < 8; nt++) {
            bf16x8 b = *(const bf16x8*)(wrz + (nt * 16 + nrow) * WRZST + ks * 64 + quad * 16);
            accrz[0][nt] = MFMA16(a0, b, accrz[0][nt]);
            accrz[1][nt] = MFMA16(a1, b, accrz[1][nt]);
        }
        if (ks < 2) {
#pragma unroll
            for (int nt = 0; nt < 4; nt++) {
                bf16x8 b = *(const bf16x8*)(wni + (nt * 16 + nrow) * WNST + ks * 64 + quad * 16);
                acci[0][nt] = MFMA16(a0, b, acci[0][nt]);
                acci[1][nt] = MFMA16(a1, b, acci[1][nt]);
            }
        } else {
#pragma unroll
            for (int nt = 0; nt < 4; nt++) {
                bf16x8 b = *(const bf16x8*)(wnh + (nt * 16 + nrow) * WNST + (ks - 2) * 64 + quad * 16);
                acch[0][nt] = MFMA16(a0, b, acch[0][nt]);
                acch[1][nt] = MFMA16(a1, b, acch[1][nt]);
            }
        }
    }

#pragma unroll
    for (int mt = 0; mt < 2; mt++)
#pragma unroll
        for (int nt = 0; nt < 4; nt++)
#pragma unroll
            for (int rg = 0; rg < 4; rg++) {
                int node = nb0 + mt * 16 + quad * 4 + rg;
                if (node < N) {
                    int col = nt * 16 + nrow;
                    float r = fast_sig(accrz[mt][nt][rg]);
                    float z = fast_sig(accrz[mt][nt + 4][rg]);
                    float nn = fast_tanh(acci[mt][nt][rg] + r * acch[mt][nt][rg]);
                    size_t idx = (size_t)node * 64 + col;
                    float ho = h[idx];
                    float hnew = (1.f - z) * nn + z * ho;
                    h[idx] = hnew;
                    hb[idx] = f2bf(hnew);
                }
            }
}

extern "C" void kernel_launch(void* const* d_in, const int* in_sizes, int n_in,
                              void* d_out, int out_size, void* d_ws, size_t ws_size,
                              hipStream_t stream) {
    const int* edge_index = (const int*)d_in[0];
    int E = in_sizes[0] / 2;
    const int* src = edge_index;
    const int* dst = edge_index + E;
    const int* kinds = (const int*)d_in[1];
    int N = in_sizes[1];
    const float* edge_attr = (const float*)d_in[2];
    const float* emb = (const float*)d_in[3];
    const float* msg_w1 = (const float*)d_in[4];
    const float* msg_b1 = (const float*)d_in[5];
    const float* msg_w2 = (const float*)d_in[6];
    const float* msg_b2 = (const float*)d_in[7];
    const float* gru_wih = (const float*)d_in[8];
    const float* gru_whh = (const float*)d_in[9];
    const float* gru_bih = (const float*)d_in[10];
    const float* gru_bhh = (const float*)d_in[11];
    const float* head_w1 = (const float*)d_in[12];
    const float* head_b1 = (const float*)d_in[13];
    const float* head_w2 = (const float*)d_in[14];
    const float* head_b2 = (const float*)d_in[15];
    float* out = (float*)d_out;

    // workspace carve-up
    char* p = (char*)d_ws;
    float* h = (float*)p;        p += (size_t)N * 64 * 4;
    float* agg = (float*)p;      p += (size_t)N * 64 * 4;
    int* deg = (int*)p;          p += (size_t)N * 4;
    int* cursor = (int*)p;       p += (size_t)N * 4;
    int* src_s = (int*)p;        p += (size_t)E * 4;
    int* dst_s = (int*)p;        p += (size_t)E * 4;
    ushort* hb = (ushort*)p;     p += (size_t)N * 64 * 2;
    ushort* Wb1 = (ushort*)p;    p += 30720 * 2;
    ushort* Wb2 = (ushort*)p;    p += 12288 * 2;
    ushort* Wh1 = (ushort*)p;    p += 10240 * 2;
    ushort* Wh2b = (ushort*)p;   p += 1024 * 2;
    ushort* Wrz = (ushort*)p;    p += 49152 * 2;
    ushort* Wni = (ushort*)p;    p += 12288 * 2;
    ushort* Wnh = (ushort*)p;    p += 12288 * 2;
    ushort* ea_sb = (ushort*)p;  p += (size_t)E * 4 * 2;

    int nchunks = (E + CHUNK - 1) / CHUNK;

    prep_kernel<<<500, 256, 0, stream>>>(msg_w1, msg_b1, msg_w2, gru_wih, gru_whh,
                                         head_w1, head_b1, head_w2,
                                         Wb1, Wb2, Wh1, Wh2b, Wrz, Wni, Wnh);
    embed_kernel<<<(N * 64 + 255) / 256, 256, 0, stream>>>(h, hb, emb, kinds, N);

    hipMemsetAsync(deg, 0, (size_t)N * sizeof(int), stream);
    hist_kernel<<<(E + 255) / 256, 256, 0, stream>>>(dst, deg, E);
    scan_kernel<<<1, 1024, 0, stream>>>(deg, cursor, N);
    scatter_kernel<<<(E + 255) / 256, 256, 0, stream>>>(src, dst, edge_attr, cursor,
                                                        src_s, dst_s, ea_sb, E);

    for (int l = 0; l < 3; l++) {
        hipMemsetAsync(agg, 0, (size_t)N * 64 * sizeof(float), stream);
        edge_msg_mfma<<<1024, 256, 0, stream>>>(
            hb, src_s, dst_s, ea_sb,
            Wb1 + l * 10240, Wb2 + l * 4096,
            msg_b2 + l * 64, agg, E, nchunks);
        gru_mfma<<<(N + 127) / 128, 256, 0, stream>>>(
            h, hb, agg, Wrz + l * 16384, Wni + l * 4096, Wnh + l * 4096,
            gru_bih + l * 192, gru_bhh + l * 192, N);
    }
    head_mfma<<<1024, 256, 0, stream>>>(hb, src, dst, edge_attr, Wh1, Wh2b,
                                        head_b2, out, E, nchunks);
}

// Round 14
// 674.626 us; speedup vs baseline: 1.0225x; 1.0225x over previous
//
#include <hip/hip_runtime.h>
#include <hip/hip_bf16.h>

// ---------------------------------------------------------------------------
// HazardGNN FINAL (= rounds 11/14, best verified: 667.9 / 671.6 us total).
// r4 LDS-slab structure + two verified edits:
//  (a) GEMM1 operand-swapped (W1 as A-operand) -> silu epilogue packs via
//      v_cvt_pk_bf16_f32 into 8x8B hid writes instead of 32 scalar b16.
//  (b) bias folded into W1 as two ones-columns (k=132 hi + k=133 residual).
// Closed levers (all tested, all regressed, mechanisms understood):
//  - grouped reduce (2x atomic/WRITE traffic), direct per-lane gather (loses
//    to slab copy), min-waves launch bounds (unified-regfile split -> spills,
//    3x), LDS overlay shrink (no occupancy gain; limiter is reg/AGPR side),
//    grids != 512 (cold-block weight reload > tail smoothing), index prefetch
//    (live-range growth). Grid 512 = 2 blocks/CU, warm weights, 12 chunks ea.
// ---------------------------------------------------------------------------

typedef __attribute__((ext_vector_type(8))) short bf16x8;
typedef __attribute__((ext_vector_type(4))) float f32x4;
#define MFMA16(a, b, c) __builtin_amdgcn_mfma_f32_16x16x32_bf16(a, b, c, 0, 0, 0)

#define CHUNK 128
#define XSTRIDE 336   // bytes per x row: 168 bf16 (K padded to 160, +8 slack)
#define MSTRIDE 264   // bytes per m row: 66 f32
#define HSTRIDE 144   // bytes per hid row: 72 bf16
#define SLABSZ 10752  // 32 * XSTRIDE
#define HIDSZ  4608   // 32 * HSTRIDE

// GRU LDS strides (+8 bf16 pad to break power-of-2 banking)
#define WRZST 264     // 128 bf16 + 4 pad
#define WNST  136     // 64 bf16 + 4 pad

__device__ __forceinline__ float fast_sig(float x) { return 1.f / (1.f + __expf(-x)); }
__device__ __forceinline__ float fast_tanh(float x) {
    float ax = fabsf(x);
    float t = __expf(-2.f * ax);
    return copysignf((1.f - t) / (1.f + t), x);
}
__device__ __forceinline__ ushort f2bf(float f) {  // RNE fp32->bf16
    unsigned u = __float_as_uint(f);
    unsigned r = u + 0x7FFF + ((u >> 16) & 1);
    return (ushort)(r >> 16);
}
__device__ __forceinline__ float bf2f(ushort b) {
    return __uint_as_float(((unsigned)b) << 16);
}
__device__ __forceinline__ unsigned pkbf2(float a, float b) {  // 2xf32 -> packed bf16 (RNE)
    unsigned r;
    asm("v_cvt_pk_bf16_f32 %0, %1, %2" : "=v"(r) : "v"(a), "v"(b));
    return r;
}

// ---------------------------------------------------------------------------
// prep: bf16 weight images. W1 images carry the layer bias in two
// ones-columns: k=132 -> bf16(b), k=133 -> bf16(b - fp32(bf16(b))).
// ---------------------------------------------------------------------------
__global__ void prep_kernel(const float* __restrict__ msg_w1,
                            const float* __restrict__ msg_b1,
                            const float* __restrict__ msg_w2,
                            const float* __restrict__ gru_wih,
                            const float* __restrict__ gru_whh,
                            const float* __restrict__ head_w1,
                            const float* __restrict__ head_b1,
                            const float* __restrict__ head_w2,
                            ushort* __restrict__ Wb1, ushort* __restrict__ Wb2,
                            ushort* __restrict__ Wh1, ushort* __restrict__ Wh2b,
                            ushort* __restrict__ Wrz, ushort* __restrict__ Wni,
                            ushort* __restrict__ Wnh) {
    int t = blockIdx.x * 256 + threadIdx.x;
    if (t < 30720) {  // Wb1[l][j][k<160]
        int l = t / 10240, r = t % 10240, j = r / 160, k = r % 160;
        float v = 0.f;
        if (k < 132) {
            v = msg_w1[l * 8448 + j * 132 + k];
        } else if (k == 132) {
            v = msg_b1[l * 64 + j];
        } else if (k == 133) {
            float b = msg_b1[l * 64 + j];
            v = b - bf2f(f2bf(b));
        }
        Wb1[t] = f2bf(v);
        return;
    }
    t -= 30720;
    if (t < 12288) {  // Wb2[l][j][k<64]
        Wb2[t] = f2bf(msg_w2[t]);
        return;
    }
    t -= 12288;
    if (t < 10240) {  // Wh1[j][k<160]
        int j = t / 160, k = t % 160;
        float v = 0.f;
        if (k < 132) {
            v = head_w1[j * 132 + k];
        } else if (k == 132) {
            v = head_b1[j];
        } else if (k == 133) {
            float b = head_b1[j];
            v = b - bf2f(f2bf(b));
        }
        Wh1[t] = f2bf(v);
        return;
    }
    t -= 10240;
    if (t < 1024) {  // Wh2b[16][64]: row 0 = head_w2, rows 1..15 zero
        int j = t >> 6, k = t & 63;
        Wh2b[t] = (j == 0) ? f2bf(head_w2[k]) : 0;
        return;
    }
    t -= 1024;
    if (t < 49152) {  // Wrz[l][n][k]
        int l = t / 16384, r = t % 16384, n = r >> 7, k = r & 127;
        float v = (k < 64) ? gru_wih[l * 12288 + n * 64 + k]
                           : gru_whh[l * 12288 + n * 64 + (k - 64)];
        Wrz[t] = f2bf(v);
        return;
    }
    t -= 49152;
    if (t < 12288) {  // Wni[l][j][k]
        int l = t / 4096, r = t % 4096, j = r >> 6, k = r & 63;
        Wni[t] = f2bf(gru_wih[l * 12288 + (128 + j) * 64 + k]);
        return;
    }
    t -= 12288;
    if (t < 12288) {  // Wnh[l][j][k]
        int l = t / 4096, r = t % 4096, j = r >> 6, k = r & 63;
        Wnh[t] = f2bf(gru_whh[l * 12288 + (128 + j) * 64 + k]);
    }
}

// h (fp32) + hb (bf16 mirror) from embedding
__global__ void embed_kernel(float* __restrict__ h, ushort* __restrict__ hb,
                             const float* __restrict__ emb,
                             const int* __restrict__ kinds, int N) {
    int t = blockIdx.x * 256 + threadIdx.x;
    if (t >= N * 64) return;
    int node = t >> 6, d = t & 63;
    float v = emb[kinds[node] * 64 + d];
    h[t] = v;
    hb[t] = f2bf(v);
}

// -------------------- counting sort by dst --------------------
__global__ void hist_kernel(const int* __restrict__ dst, int* __restrict__ deg, int E) {
    int e = blockIdx.x * 256 + threadIdx.x;
    if (e < E) atomicAdd(&deg[dst[e]], 1);
}

__global__ void scan_kernel(const int* __restrict__ deg, int* __restrict__ cursor, int N) {
    __shared__ int sums[1024];
    int tid = threadIdx.x;
    int chunk = (N + 1023) >> 10;
    int lo = tid * chunk, hi = min(lo + chunk, N);
    int s = 0;
    for (int i = lo; i < hi; i++) s += deg[i];
    sums[tid] = s;
    __syncthreads();
    for (int off = 1; off < 1024; off <<= 1) {
        int v = (tid >= off) ? sums[tid - off] : 0;
        __syncthreads();
        sums[tid] += v;
        __syncthreads();
    }
    int run = (tid > 0) ? sums[tid - 1] : 0;
    for (int i = lo; i < hi; i++) {
        cursor[i] = run;
        run += deg[i];
    }
}

__global__ void scatter_kernel(const int* __restrict__ src, const int* __restrict__ dst,
                               const float* __restrict__ ea, int* __restrict__ cursor,
                               int* __restrict__ src_s, int* __restrict__ dst_s,
                               ushort* __restrict__ ea_sb, int E) {
    int e = blockIdx.x * 256 + threadIdx.x;
    if (e >= E) return;
    int d = dst[e];
    int p = atomicAdd(&cursor[d], 1);
    src_s[p] = src[e];
    dst_s[p] = d;
    float4 e4 = ((const float4*)ea)[e];
    ushort4 eb;
    eb.x = f2bf(e4.x); eb.y = f2bf(e4.y); eb.z = f2bf(e4.z); eb.w = f2bf(e4.w);
    ((ushort4*)ea_sb)[p] = eb;
}

// ---------------------------------------------------------------------------
// edge message kernel: r4 slab structure, GEMM1 swapped + cvt_pk epilogue.
// ---------------------------------------------------------------------------
__global__ __launch_bounds__(256) void edge_msg_mfma(
    const ushort* __restrict__ hb, const int* __restrict__ src_s,
    const int* __restrict__ dst_s, const ushort* __restrict__ ea_sb,
    const ushort* __restrict__ Wb1l, const ushort* __restrict__ Wb2l,
    const float* __restrict__ b2,
    float* __restrict__ agg, int E, int nchunks) {
    __shared__ char lds[4 * SLABSZ + 4 * HIDSZ];  // 61440 B
    int tid = threadIdx.x;
    int w = tid >> 6, lane = tid & 63;
    int quad = lane >> 4, nrow = lane & 15;
    char* slab = lds + w * SLABSZ;
    char* hidb = lds + 4 * SLABSZ + w * HIDSZ;

    bf16x8 wf1[4][5], wf2[4][2];
    float b2v[4];
#pragma unroll
    for (int nt = 0; nt < 4; nt++) {
        int n = nt * 16 + nrow;
#pragma unroll
        for (int ks = 0; ks < 5; ks++)
            wf1[nt][ks] = *(const bf16x8*)(Wb1l + n * 160 + ks * 32 + quad * 8);
#pragma unroll
        for (int ks = 0; ks < 2; ks++)
            wf2[nt][ks] = *(const bf16x8*)(Wb2l + n * 64 + ks * 32 + quad * 8);
        b2v[nt] = b2[n];
    }

    for (int chunk = blockIdx.x; chunk < nchunks; chunk += gridDim.x) {
        int ebase = chunk * CHUNK;
        {
            int el = tid >> 1, half = tid & 1;
            int r = el & 31;
            int ec = min(ebase + el, E - 1);
            int node = half ? dst_s[ec] : src_s[ec];
            const float4* hrow = (const float4*)(hb + (size_t)node * 64);
            float4* xw = (float4*)(slab + r * XSTRIDE + half * 128);
#pragma unroll
            for (int i = 0; i < 8; i++) xw[i] = hrow[i];
            if (half == 0) {
                *(uint2*)(slab + r * XSTRIDE + 256) = *(const uint2*)(ea_sb + (size_t)ec * 4);
            } else {
                // k=132,133 = 1.0 (bias ones-columns); k=134.. zero
                uint2 ones2 = {0x3F803F80u, 0u};
                float4 z4 = {0.f, 0.f, 0.f, 0.f};
                *(uint2*)(slab + r * XSTRIDE + 264) = ones2;
                *(float4*)(slab + r * XSTRIDE + 272) = z4;
                *(float4*)(slab + r * XSTRIDE + 288) = z4;
                *(float4*)(slab + r * XSTRIDE + 304) = z4;
            }
        }
        // GEMM1 (swapped): acc1[nt][et], C row = n (nt*16+quad*4+rg),
        // col = edge (et*16+nrow). Bias comes from the ones-columns.
        f32x4 acc1[4][2];
#pragma unroll
        for (int nt = 0; nt < 4; nt++) {
            f32x4 z4;
            z4[0] = z4[1] = z4[2] = z4[3] = 0.f;
            acc1[nt][0] = z4;
            acc1[nt][1] = z4;
        }
#pragma unroll
        for (int ks = 0; ks < 5; ks++) {
            bf16x8 xb0 = *(const bf16x8*)(slab + nrow * XSTRIDE + ks * 64 + quad * 16);
            bf16x8 xb1 = *(const bf16x8*)(slab + (16 + nrow) * XSTRIDE + ks * 64 + quad * 16);
#pragma unroll
            for (int nt = 0; nt < 4; nt++) {
                acc1[nt][0] = MFMA16(wf1[nt][ks], xb0, acc1[nt][0]);
                acc1[nt][1] = MFMA16(wf1[nt][ks], xb1, acc1[nt][1]);
            }
        }
        // silu -> packed bf16 -> hid[edge][n] (8B stores, HSTRIDE breaks banks)
#pragma unroll
        for (int nt = 0; nt < 4; nt++)
#pragma unroll
            for (int et = 0; et < 2; et++) {
                f32x4 a = acc1[nt][et];
                float v0 = a[0] * fast_sig(a[0]);
                float v1 = a[1] * fast_sig(a[1]);
                float v2 = a[2] * fast_sig(a[2]);
                float v3 = a[3] * fast_sig(a[3]);
                int er = et * 16 + nrow;
                uint2 pk;
                pk.x = pkbf2(v0, v1);
                pk.y = pkbf2(v2, v3);
                *(uint2*)(hidb + er * HSTRIDE + nt * 32 + quad * 8) = pk;
            }
        // GEMM2 (unswapped): C[edge][n2]
        f32x4 acc2[2][4];
#pragma unroll
        for (int mt = 0; mt < 2; mt++)
#pragma unroll
            for (int nt = 0; nt < 4; nt++) {
                f32x4 v;
                v[0] = v[1] = v[2] = v[3] = b2v[nt];
                acc2[mt][nt] = v;
            }
#pragma unroll
        for (int ks = 0; ks < 2; ks++) {
            bf16x8 a0 = *(const bf16x8*)(hidb + nrow * HSTRIDE + ks * 64 + quad * 16);
            bf16x8 a1 = *(const bf16x8*)(hidb + (16 + nrow) * HSTRIDE + ks * 64 + quad * 16);
#pragma unroll
            for (int nt = 0; nt < 4; nt++) {
                acc2[0][nt] = MFMA16(a0, wf2[nt][ks], acc2[0][nt]);
                acc2[1][nt] = MFMA16(a1, wf2[nt][ks], acc2[1][nt]);
            }
        }
#pragma unroll
        for (int mt = 0; mt < 2; mt++)
#pragma unroll
            for (int nt = 0; nt < 4; nt++)
#pragma unroll
                for (int rg = 0; rg < 4; rg++) {
                    int rm = mt * 16 + quad * 4 + rg;
                    *(float*)(slab + rm * MSTRIDE + (nt * 16 + nrow) * 4) = acc2[mt][nt][rg];
                }
        {
            int e32 = ebase + w * 32;
            int dmy = dst_s[min(e32 + (lane & 31), E - 1)];
            int limit = min(32, E - e32);
            int nx = __shfl_down(dmy, 1);
            bool tl = ((lane & 31) == 31) || (dmy != nx);
            unsigned long long tm = __ballot(tl);
            float run = 0.f;
#pragma unroll
            for (int i = 0; i < 32; i++) {
                if (i < limit) {
                    run += *(const float*)(slab + i * MSTRIDE + lane * 4);
                    if (((tm >> i) & 1ull) || (i + 1 == limit)) {
                        int di = __shfl(dmy, i);
                        unsafeAtomicAdd(&agg[(size_t)di * 64 + lane], run);
                        run = 0.f;
                    }
                }
            }
        }
    }
}

// ---------------------------------------------------------------------------
// head kernel: r4 slab structure, GEMM1 swapped + cvt_pk epilogue.
// ---------------------------------------------------------------------------
__global__ __launch_bounds__(256) void head_mfma(
    const ushort* __restrict__ hb, const int* __restrict__ src,
    const int* __restrict__ dst, const float* __restrict__ ea,
    const ushort* __restrict__ Wh1, const ushort* __restrict__ Wh2b,
    const float* __restrict__ hb2p,
    float* __restrict__ out, int E, int nchunks) {
    __shared__ char lds[4 * SLABSZ + 4 * HIDSZ];
    int tid = threadIdx.x;
    int w = tid >> 6, lane = tid & 63;
    int quad = lane >> 4, nrow = lane & 15;
    char* slab = lds + w * SLABSZ;
    char* hidb = lds + 4 * SLABSZ + w * HIDSZ;

    bf16x8 wf1[4][5], wh2[2];
#pragma unroll
    for (int nt = 0; nt < 4; nt++) {
        int n = nt * 16 + nrow;
#pragma unroll
        for (int ks = 0; ks < 5; ks++)
            wf1[nt][ks] = *(const bf16x8*)(Wh1 + n * 160 + ks * 32 + quad * 8);
    }
#pragma unroll
    for (int ks = 0; ks < 2; ks++)
        wh2[ks] = *(const bf16x8*)(Wh2b + nrow * 64 + ks * 32 + quad * 8);
    float hb2 = hb2p[0];

    for (int chunk = blockIdx.x; chunk < nchunks; chunk += gridDim.x) {
        int ebase = chunk * CHUNK;
        {
            int el = tid >> 1, half = tid & 1;
            int r = el & 31;
            int ec = min(ebase + el, E - 1);
            int node = half ? dst[ec] : src[ec];
            const float4* hrow = (const float4*)(hb + (size_t)node * 64);
            float4* xw = (float4*)(slab + r * XSTRIDE + half * 128);
#pragma unroll
            for (int i = 0; i < 8; i++) xw[i] = hrow[i];
            if (half == 0) {
                float4 e4 = ((const float4*)ea)[ec];
                ushort4 eb;
                eb.x = f2bf(e4.x); eb.y = f2bf(e4.y); eb.z = f2bf(e4.z); eb.w = f2bf(e4.w);
                *(ushort4*)(slab + r * XSTRIDE + 256) = eb;
            } else {
                uint2 ones2 = {0x3F803F80u, 0u};
                float4 z4 = {0.f, 0.f, 0.f, 0.f};
                *(uint2*)(slab + r * XSTRIDE + 264) = ones2;
                *(float4*)(slab + r * XSTRIDE + 272) = z4;
                *(float4*)(slab + r * XSTRIDE + 288) = z4;
                *(float4*)(slab + r * XSTRIDE + 304) = z4;
            }
        }
        f32x4 acc1[4][2];
#pragma unroll
        for (int nt = 0; nt < 4; nt++) {
            f32x4 z4;
            z4[0] = z4[1] = z4[2] = z4[3] = 0.f;
            acc1[nt][0] = z4;
            acc1[nt][1] = z4;
        }
#pragma unroll
        for (int ks = 0; ks < 5; ks++) {
            bf16x8 xb0 = *(const bf16x8*)(slab + nrow * XSTRIDE + ks * 64 + quad * 16);
            bf16x8 xb1 = *(const bf16x8*)(slab + (16 + nrow) * XSTRIDE + ks * 64 + quad * 16);
#pragma unroll
            for (int nt = 0; nt < 4; nt++) {
                acc1[nt][0] = MFMA16(wf1[nt][ks], xb0, acc1[nt][0]);
                acc1[nt][1] = MFMA16(wf1[nt][ks], xb1, acc1[nt][1]);
            }
        }
#pragma unroll
        for (int nt = 0; nt < 4; nt++)
#pragma unroll
            for (int et = 0; et < 2; et++) {
                f32x4 a = acc1[nt][et];
                float v0 = a[0] * fast_sig(a[0]);
                float v1 = a[1] * fast_sig(a[1]);
                float v2 = a[2] * fast_sig(a[2]);
                float v3 = a[3] * fast_sig(a[3]);
                int er = et * 16 + nrow;
                uint2 pk;
                pk.x = pkbf2(v0, v1);
                pk.y = pkbf2(v2, v3);
                *(uint2*)(hidb + er * HSTRIDE + nt * 32 + quad * 8) = pk;
            }
        f32x4 acc3[2];
#pragma unroll
        for (int mt = 0; mt < 2; mt++) {
            f32x4 v;
            v[0] = v[1] = v[2] = v[3] = 0.f;
            acc3[mt] = v;
        }
#pragma unroll
        for (int ks = 0; ks < 2; ks++) {
            bf16x8 a0 = *(const bf16x8*)(hidb + nrow * HSTRIDE + ks * 64 + quad * 16);
            bf16x8 a1 = *(const bf16x8*)(hidb + (16 + nrow) * HSTRIDE + ks * 64 + quad * 16);
            acc3[0] = MFMA16(a0, wh2[ks], acc3[0]);
            acc3[1] = MFMA16(a1, wh2[ks], acc3[1]);
        }
        if (nrow == 0) {
#pragma unroll
            for (int mt = 0; mt < 2; mt++)
#pragma unroll
                for (int rg = 0; rg < 4; rg++) {
                    int e = ebase + w * 32 + mt * 16 + quad * 4 + rg;
                    if (e < E) out[e] = fast_sig(acc3[mt][rg] + hb2);
                }
        }
    }
}

// ---------------------------------------------------------------------------
// GRU MFMA kernel (unchanged).
// ---------------------------------------------------------------------------
__device__ __forceinline__ bf16x8 aggfrag(const float* __restrict__ row, int off) {
    float4 f0 = *(const float4*)(row + off);
    float4 f1 = *(const float4*)(row + off + 4);
    bf16x8 r;
    r[0] = (short)f2bf(f0.x); r[1] = (short)f2bf(f0.y);
    r[2] = (short)f2bf(f0.z); r[3] = (short)f2bf(f0.w);
    r[4] = (short)f2bf(f1.x); r[5] = (short)f2bf(f1.y);
    r[6] = (short)f2bf(f1.z); r[7] = (short)f2bf(f1.w);
    return r;
}

__global__ __launch_bounds__(256) void gru_mfma(
    float* __restrict__ h, ushort* __restrict__ hb, const float* __restrict__ agg,
    const ushort* __restrict__ Wrzg, const ushort* __restrict__ Wnig,
    const ushort* __restrict__ Wnhg,
    const float* __restrict__ bih, const float* __restrict__ bhh, int N) {
    __shared__ char lds[128 * WRZST + 2 * 64 * WNST];  // 51200 B
    int tid = threadIdx.x, w = tid >> 6, lane = tid & 63;
    int quad = lane >> 4, nrow = lane & 15;
    char* wrz = lds;
    char* wni = lds + 128 * WRZST;
    char* wnh = wni + 64 * WNST;

    {
        int r = tid >> 1, half = tid & 1;
        const uint4* g = (const uint4*)(Wrzg + r * 128 + half * 64);
        uint4* d = (uint4*)(wrz + r * WRZST + half * 128);
#pragma unroll
        for (int i = 0; i < 8; i++) d[i] = g[i];
        if (tid < 128) {
            const uint4* g2 = (const uint4*)(Wnig + (tid >> 1) * 64 + (tid & 1) * 32);
            uint4* d2 = (uint4*)(wni + (tid >> 1) * WNST + (tid & 1) * 64);
#pragma unroll
            for (int i = 0; i < 4; i++) d2[i] = g2[i];
        } else {
            int t2 = tid - 128;
            const uint4* g2 = (const uint4*)(Wnhg + (t2 >> 1) * 64 + (t2 & 1) * 32);
            uint4* d2 = (uint4*)(wnh + (t2 >> 1) * WNST + (t2 & 1) * 64);
#pragma unroll
            for (int i = 0; i < 4; i++) d2[i] = g2[i];
        }
    }
    __syncthreads();

    int nb0 = blockIdx.x * 128 + w * 32;
    if (nb0 >= N) return;

    float brz[8], bi[4], bhv[4];
#pragma unroll
    for (int nt = 0; nt < 8; nt++) brz[nt] = bih[nt * 16 + nrow] + bhh[nt * 16 + nrow];
#pragma unroll
    for (int nt = 0; nt < 4; nt++) {
        bi[nt] = bih[128 + nt * 16 + nrow];
        bhv[nt] = bhh[128 + nt * 16 + nrow];
    }

    int n0 = min(nb0 + nrow, N - 1);
    int n1 = min(nb0 + 16 + nrow, N - 1);
    const float* ag0 = agg + (size_t)n0 * 64;
    const float* ag1 = agg + (size_t)n1 * 64;
    const ushort* hb0 = hb + (size_t)n0 * 64;
    const ushort* hb1 = hb + (size_t)n1 * 64;

    f32x4 accrz[2][8], acci[2][4], acch[2][4];
#pragma unroll
    for (int nt = 0; nt < 8; nt++) {
        f32x4 v; v[0] = v[1] = v[2] = v[3] = brz[nt];
        accrz[0][nt] = v; accrz[1][nt] = v;
    }
#pragma unroll
    for (int nt = 0; nt < 4; nt++) {
        f32x4 vi; vi[0] = vi[1] = vi[2] = vi[3] = bi[nt];
        acci[0][nt] = vi; acci[1][nt] = vi;
        f32x4 vh; vh[0] = vh[1] = vh[2] = vh[3] = bhv[nt];
        acch[0][nt] = vh; acch[1][nt] = vh;
    }

#pragma unroll
    for (int ks = 0; ks < 4; ks++) {
        bf16x8 a0, a1;
        if (ks < 2) {
            a0 = aggfrag(ag0, ks * 32 + quad * 8);
            a1 = aggfrag(ag1, ks * 32 + quad * 8);
        } else {
            a0 = *(const bf16x8*)(hb0 + (ks - 2) * 32 + quad * 8);
            a1 = *(const bf16x8*)(hb1 + (ks - 2) * 32 + quad * 8);
        }
#pragma unroll
        for (int nt = 0; nt < 8; nt++) {
            bf16x8 b = *(const bf16x8*)(wrz + (nt * 16 + nrow) * WRZST + ks * 64 + quad * 16);
            accrz[0][nt] = MFMA16(a0, b, accrz[0][nt]);
            accrz[1][nt] = MFMA16(a1, b, accrz[1][nt]);
        }
        if (ks < 2) {
#pragma unroll
            for (int nt = 0; nt < 4; nt++) {
                bf16x8 b = *(const bf16x8*)(wni + (nt * 16 + nrow) * WNST + ks * 64 + quad * 16);
                acci[0][nt] = MFMA16(a0, b, acci[0][nt]);
                acci[1][nt] = MFMA16(a1, b, acci[1][nt]);
            }
        } else {
#pragma unroll
            for (int nt = 0; nt < 4; nt++) {
                bf16x8 b = *(const bf16x8*)(wnh + (nt * 16 + nrow) * WNST + (ks - 2) * 64 + quad * 16);
                acch[0][nt] = MFMA16(a0, b, acch[0][nt]);
                acch[1][nt] = MFMA16(a1, b, acch[1][nt]);
            }
        }
    }

#pragma unroll
    for (int mt = 0; mt < 2; mt++)
#pragma unroll
        for (int nt = 0; nt < 4; nt++)
#pragma unroll
            for (int rg = 0; rg < 4; rg++) {
                int node = nb0 + mt * 16 + quad * 4 + rg;
                if (node < N) {
                    int col = nt * 16 + nrow;
                    float r = fast_sig(accrz[mt][nt][rg]);
                    float z = fast_sig(accrz[mt][nt + 4][rg]);
                    float nn = fast_tanh(acci[mt][nt][rg] + r * acch[mt][nt][rg]);
                    size_t idx = (size_t)node * 64 + col;
                    float ho = h[idx];
                    float hnew = (1.f - z) * nn + z * ho;
                    h[idx] = hnew;
                    hb[idx] = f2bf(hnew);
                }
            }
}

extern "C" void kernel_launch(void* const* d_in, const int* in_sizes, int n_in,
                              void* d_out, int out_size, void* d_ws, size_t ws_size,
                              hipStream_t stream) {
    const int* edge_index = (const int*)d_in[0];
    int E = in_sizes[0] / 2;
    const int* src = edge_index;
    const int* dst = edge_index + E;
    const int* kinds = (const int*)d_in[1];
    int N = in_sizes[1];
    const float* edge_attr = (const float*)d_in[2];
    const float* emb = (const float*)d_in[3];
    const float* msg_w1 = (const float*)d_in[4];
    const float* msg_b1 = (const float*)d_in[5];
    const float* msg_w2 = (const float*)d_in[6];
    const float* msg_b2 = (const float*)d_in[7];
    const float* gru_wih = (const float*)d_in[8];
    const float* gru_whh = (const float*)d_in[9];
    const float* gru_bih = (const float*)d_in[10];
    const float* gru_bhh = (const float*)d_in[11];
    const float* head_w1 = (const float*)d_in[12];
    const float* head_b1 = (const float*)d_in[13];
    const float* head_w2 = (const float*)d_in[14];
    const float* head_b2 = (const float*)d_in[15];
    float* out = (float*)d_out;

    // workspace carve-up
    char* p = (char*)d_ws;
    float* h = (float*)p;        p += (size_t)N * 64 * 4;
    float* agg = (float*)p;      p += (size_t)N * 64 * 4;
    int* deg = (int*)p;          p += (size_t)N * 4;
    int* cursor = (int*)p;       p += (size_t)N * 4;
    int* src_s = (int*)p;        p += (size_t)E * 4;
    int* dst_s = (int*)p;        p += (size_t)E * 4;
    ushort* hb = (ushort*)p;     p += (size_t)N * 64 * 2;
    ushort* Wb1 = (ushort*)p;    p += 30720 * 2;
    ushort* Wb2 = (ushort*)p;    p += 12288 * 2;
    ushort* Wh1 = (ushort*)p;    p += 10240 * 2;
    ushort* Wh2b = (ushort*)p;   p += 1024 * 2;
    ushort* Wrz = (ushort*)p;    p += 49152 * 2;
    ushort* Wni = (ushort*)p;    p += 12288 * 2;
    ushort* Wnh = (ushort*)p;    p += 12288 * 2;
    ushort* ea_sb = (ushort*)p;  p += (size_t)E * 4 * 2;

    int nchunks = (E + CHUNK - 1) / CHUNK;

    prep_kernel<<<500, 256, 0, stream>>>(msg_w1, msg_b1, msg_w2, gru_wih, gru_whh,
                                         head_w1, head_b1, head_w2,
                                         Wb1, Wb2, Wh1, Wh2b, Wrz, Wni, Wnh);
    embed_kernel<<<(N * 64 + 255) / 256, 256, 0, stream>>>(h, hb, emb, kinds, N);

    hipMemsetAsync(deg, 0, (size_t)N * sizeof(int), stream);
    hist_kernel<<<(E + 255) / 256, 256, 0, stream>>>(dst, deg, E);
    scan_kernel<<<1, 1024, 0, stream>>>(deg, cursor, N);
    scatter_kernel<<<(E + 255) / 256, 256, 0, stream>>>(src, dst, edge_attr, cursor,
                                                        src_s, dst_s, ea_sb, E);

    for (int l = 0; l < 3; l++) {
        hipMemsetAsync(agg, 0, (size_t)N * 64 * sizeof(float), stream);
        edge_msg_mfma<<<512, 256, 0, stream>>>(
            hb, src_s, dst_s, ea_sb,
            Wb1 + l * 10240, Wb2 + l * 4096,
            msg_b2 + l * 64, agg, E, nchunks);
        gru_mfma<<<(N + 127) / 128, 256, 0, stream>>>(
            h, hb, agg, Wrz + l * 16384, Wni + l * 4096, Wnh + l * 4096,
            gru_bih + l * 192, gru_bhh + l * 192, N);
    }
    head_mfma<<<512, 256, 0, stream>>>(hb, src, dst, edge_attr, Wh1, Wh2b,
                                       head_b2, out, E, nchunks);
}

// Round 15
// 653.478 us; speedup vs baseline: 1.0556x; 1.0324x over previous
//
#include <hip/hip_runtime.h>
#include <hip/hip_bf16.h>

// ---------------------------------------------------------------------------
// HazardGNN round 17: edge/head kernels byte-identical to the verified best
// (r11/r14: 667.9/671.6/674.6 us). New: GRU residency fix + memset fold.
//  - gru_mfma: 64 nodes/block (4 waves x 16 nodes, single M-tile/wave).
//    Old grid 391 blocks = 1.5 blocks/CU vs LDS capacity 3 -> half the
//    residency slots empty on a latency-bound kernel. New grid 782 = 3.05
//    blocks/CU. Accumulators halve (128->64 acc regs) -> no spill risk.
//  - gru zeroes agg after reading (each (node,col) owned by exactly one
//    thread; agg loads complete before MFMA use, stores issue after) ->
//    the two in-loop agg memsets are removed (one stays for first-run init).
// ---------------------------------------------------------------------------

typedef __attribute__((ext_vector_type(8))) short bf16x8;
typedef __attribute__((ext_vector_type(4))) float f32x4;
#define MFMA16(a, b, c) __builtin_amdgcn_mfma_f32_16x16x32_bf16(a, b, c, 0, 0, 0)

#define CHUNK 128
#define XSTRIDE 336   // bytes per x row: 168 bf16 (K padded to 160, +8 slack)
#define MSTRIDE 264   // bytes per m row: 66 f32
#define HSTRIDE 144   // bytes per hid row: 72 bf16
#define SLABSZ 10752  // 32 * XSTRIDE
#define HIDSZ  4608   // 32 * HSTRIDE

// GRU LDS strides (+8 bf16 pad to break power-of-2 banking)
#define WRZST 264     // 128 bf16 + 4 pad
#define WNST  136     // 64 bf16 + 4 pad

__device__ __forceinline__ float fast_sig(float x) { return 1.f / (1.f + __expf(-x)); }
__device__ __forceinline__ float fast_tanh(float x) {
    float ax = fabsf(x);
    float t = __expf(-2.f * ax);
    return copysignf((1.f - t) / (1.f + t), x);
}
__device__ __forceinline__ ushort f2bf(float f) {  // RNE fp32->bf16
    unsigned u = __float_as_uint(f);
    unsigned r = u + 0x7FFF + ((u >> 16) & 1);
    return (ushort)(r >> 16);
}
__device__ __forceinline__ float bf2f(ushort b) {
    return __uint_as_float(((unsigned)b) << 16);
}
__device__ __forceinline__ unsigned pkbf2(float a, float b) {  // 2xf32 -> packed bf16 (RNE)
    unsigned r;
    asm("v_cvt_pk_bf16_f32 %0, %1, %2" : "=v"(r) : "v"(a), "v"(b));
    return r;
}

// ---------------------------------------------------------------------------
// prep: bf16 weight images. W1 images carry the layer bias in two
// ones-columns: k=132 -> bf16(b), k=133 -> bf16(b - fp32(bf16(b))).
// ---------------------------------------------------------------------------
__global__ void prep_kernel(const float* __restrict__ msg_w1,
                            const float* __restrict__ msg_b1,
                            const float* __restrict__ msg_w2,
                            const float* __restrict__ gru_wih,
                            const float* __restrict__ gru_whh,
                            const float* __restrict__ head_w1,
                            const float* __restrict__ head_b1,
                            const float* __restrict__ head_w2,
                            ushort* __restrict__ Wb1, ushort* __restrict__ Wb2,
                            ushort* __restrict__ Wh1, ushort* __restrict__ Wh2b,
                            ushort* __restrict__ Wrz, ushort* __restrict__ Wni,
                            ushort* __restrict__ Wnh) {
    int t = blockIdx.x * 256 + threadIdx.x;
    if (t < 30720) {  // Wb1[l][j][k<160]
        int l = t / 10240, r = t % 10240, j = r / 160, k = r % 160;
        float v = 0.f;
        if (k < 132) {
            v = msg_w1[l * 8448 + j * 132 + k];
        } else if (k == 132) {
            v = msg_b1[l * 64 + j];
        } else if (k == 133) {
            float b = msg_b1[l * 64 + j];
            v = b - bf2f(f2bf(b));
        }
        Wb1[t] = f2bf(v);
        return;
    }
    t -= 30720;
    if (t < 12288) {  // Wb2[l][j][k<64]
        Wb2[t] = f2bf(msg_w2[t]);
        return;
    }
    t -= 12288;
    if (t < 10240) {  // Wh1[j][k<160]
        int j = t / 160, k = t % 160;
        float v = 0.f;
        if (k < 132) {
            v = head_w1[j * 132 + k];
        } else if (k == 132) {
            v = head_b1[j];
        } else if (k == 133) {
            float b = head_b1[j];
            v = b - bf2f(f2bf(b));
        }
        Wh1[t] = f2bf(v);
        return;
    }
    t -= 10240;
    if (t < 1024) {  // Wh2b[16][64]: row 0 = head_w2, rows 1..15 zero
        int j = t >> 6, k = t & 63;
        Wh2b[t] = (j == 0) ? f2bf(head_w2[k]) : 0;
        return;
    }
    t -= 1024;
    if (t < 49152) {  // Wrz[l][n][k]
        int l = t / 16384, r = t % 16384, n = r >> 7, k = r & 127;
        float v = (k < 64) ? gru_wih[l * 12288 + n * 64 + k]
                           : gru_whh[l * 12288 + n * 64 + (k - 64)];
        Wrz[t] = f2bf(v);
        return;
    }
    t -= 49152;
    if (t < 12288) {  // Wni[l][j][k]
        int l = t / 4096, r = t % 4096, j = r >> 6, k = r & 63;
        Wni[t] = f2bf(gru_wih[l * 12288 + (128 + j) * 64 + k]);
        return;
    }
    t -= 12288;
    if (t < 12288) {  // Wnh[l][j][k]
        int l = t / 4096, r = t % 4096, j = r >> 6, k = r & 63;
        Wnh[t] = f2bf(gru_whh[l * 12288 + (128 + j) * 64 + k]);
    }
}

// h (fp32) + hb (bf16 mirror) from embedding
__global__ void embed_kernel(float* __restrict__ h, ushort* __restrict__ hb,
                             const float* __restrict__ emb,
                             const int* __restrict__ kinds, int N) {
    int t = blockIdx.x * 256 + threadIdx.x;
    if (t >= N * 64) return;
    int node = t >> 6, d = t & 63;
    float v = emb[kinds[node] * 64 + d];
    h[t] = v;
    hb[t] = f2bf(v);
}

// -------------------- counting sort by dst --------------------
__global__ void hist_kernel(const int* __restrict__ dst, int* __restrict__ deg, int E) {
    int e = blockIdx.x * 256 + threadIdx.x;
    if (e < E) atomicAdd(&deg[dst[e]], 1);
}

__global__ void scan_kernel(const int* __restrict__ deg, int* __restrict__ cursor, int N) {
    __shared__ int sums[1024];
    int tid = threadIdx.x;
    int chunk = (N + 1023) >> 10;
    int lo = tid * chunk, hi = min(lo + chunk, N);
    int s = 0;
    for (int i = lo; i < hi; i++) s += deg[i];
    sums[tid] = s;
    __syncthreads();
    for (int off = 1; off < 1024; off <<= 1) {
        int v = (tid >= off) ? sums[tid - off] : 0;
        __syncthreads();
        sums[tid] += v;
        __syncthreads();
    }
    int run = (tid > 0) ? sums[tid - 1] : 0;
    for (int i = lo; i < hi; i++) {
        cursor[i] = run;
        run += deg[i];
    }
}

__global__ void scatter_kernel(const int* __restrict__ src, const int* __restrict__ dst,
                               const float* __restrict__ ea, int* __restrict__ cursor,
                               int* __restrict__ src_s, int* __restrict__ dst_s,
                               ushort* __restrict__ ea_sb, int E) {
    int e = blockIdx.x * 256 + threadIdx.x;
    if (e >= E) return;
    int d = dst[e];
    int p = atomicAdd(&cursor[d], 1);
    src_s[p] = src[e];
    dst_s[p] = d;
    float4 e4 = ((const float4*)ea)[e];
    ushort4 eb;
    eb.x = f2bf(e4.x); eb.y = f2bf(e4.y); eb.z = f2bf(e4.z); eb.w = f2bf(e4.w);
    ((ushort4*)ea_sb)[p] = eb;
}

// ---------------------------------------------------------------------------
// edge message kernel: r4 slab structure, GEMM1 swapped + cvt_pk epilogue.
// (byte-identical to r11/r14 verified best)
// ---------------------------------------------------------------------------
__global__ __launch_bounds__(256) void edge_msg_mfma(
    const ushort* __restrict__ hb, const int* __restrict__ src_s,
    const int* __restrict__ dst_s, const ushort* __restrict__ ea_sb,
    const ushort* __restrict__ Wb1l, const ushort* __restrict__ Wb2l,
    const float* __restrict__ b2,
    float* __restrict__ agg, int E, int nchunks) {
    __shared__ char lds[4 * SLABSZ + 4 * HIDSZ];  // 61440 B
    int tid = threadIdx.x;
    int w = tid >> 6, lane = tid & 63;
    int quad = lane >> 4, nrow = lane & 15;
    char* slab = lds + w * SLABSZ;
    char* hidb = lds + 4 * SLABSZ + w * HIDSZ;

    bf16x8 wf1[4][5], wf2[4][2];
    float b2v[4];
#pragma unroll
    for (int nt = 0; nt < 4; nt++) {
        int n = nt * 16 + nrow;
#pragma unroll
        for (int ks = 0; ks < 5; ks++)
            wf1[nt][ks] = *(const bf16x8*)(Wb1l + n * 160 + ks * 32 + quad * 8);
#pragma unroll
        for (int ks = 0; ks < 2; ks++)
            wf2[nt][ks] = *(const bf16x8*)(Wb2l + n * 64 + ks * 32 + quad * 8);
        b2v[nt] = b2[n];
    }

    for (int chunk = blockIdx.x; chunk < nchunks; chunk += gridDim.x) {
        int ebase = chunk * CHUNK;
        {
            int el = tid >> 1, half = tid & 1;
            int r = el & 31;
            int ec = min(ebase + el, E - 1);
            int node = half ? dst_s[ec] : src_s[ec];
            const float4* hrow = (const float4*)(hb + (size_t)node * 64);
            float4* xw = (float4*)(slab + r * XSTRIDE + half * 128);
#pragma unroll
            for (int i = 0; i < 8; i++) xw[i] = hrow[i];
            if (half == 0) {
                *(uint2*)(slab + r * XSTRIDE + 256) = *(const uint2*)(ea_sb + (size_t)ec * 4);
            } else {
                // k=132,133 = 1.0 (bias ones-columns); k=134.. zero
                uint2 ones2 = {0x3F803F80u, 0u};
                float4 z4 = {0.f, 0.f, 0.f, 0.f};
                *(uint2*)(slab + r * XSTRIDE + 264) = ones2;
                *(float4*)(slab + r * XSTRIDE + 272) = z4;
                *(float4*)(slab + r * XSTRIDE + 288) = z4;
                *(float4*)(slab + r * XSTRIDE + 304) = z4;
            }
        }
        // GEMM1 (swapped): acc1[nt][et], C row = n (nt*16+quad*4+rg),
        // col = edge (et*16+nrow). Bias comes from the ones-columns.
        f32x4 acc1[4][2];
#pragma unroll
        for (int nt = 0; nt < 4; nt++) {
            f32x4 z4;
            z4[0] = z4[1] = z4[2] = z4[3] = 0.f;
            acc1[nt][0] = z4;
            acc1[nt][1] = z4;
        }
#pragma unroll
        for (int ks = 0; ks < 5; ks++) {
            bf16x8 xb0 = *(const bf16x8*)(slab + nrow * XSTRIDE + ks * 64 + quad * 16);
            bf16x8 xb1 = *(const bf16x8*)(slab + (16 + nrow) * XSTRIDE + ks * 64 + quad * 16);
#pragma unroll
            for (int nt = 0; nt < 4; nt++) {
                acc1[nt][0] = MFMA16(wf1[nt][ks], xb0, acc1[nt][0]);
                acc1[nt][1] = MFMA16(wf1[nt][ks], xb1, acc1[nt][1]);
            }
        }
        // silu -> packed bf16 -> hid[edge][n] (8B stores, HSTRIDE breaks banks)
#pragma unroll
        for (int nt = 0; nt < 4; nt++)
#pragma unroll
            for (int et = 0; et < 2; et++) {
                f32x4 a = acc1[nt][et];
                float v0 = a[0] * fast_sig(a[0]);
                float v1 = a[1] * fast_sig(a[1]);
                float v2 = a[2] * fast_sig(a[2]);
                float v3 = a[3] * fast_sig(a[3]);
                int er = et * 16 + nrow;
                uint2 pk;
                pk.x = pkbf2(v0, v1);
                pk.y = pkbf2(v2, v3);
                *(uint2*)(hidb + er * HSTRIDE + nt * 32 + quad * 8) = pk;
            }
        // GEMM2 (unswapped): C[edge][n2]
        f32x4 acc2[2][4];
#pragma unroll
        for (int mt = 0; mt < 2; mt++)
#pragma unroll
            for (int nt = 0; nt < 4; nt++) {
                f32x4 v;
                v[0] = v[1] = v[2] = v[3] = b2v[nt];
                acc2[mt][nt] = v;
            }
#pragma unroll
        for (int ks = 0; ks < 2; ks++) {
            bf16x8 a0 = *(const bf16x8*)(hidb + nrow * HSTRIDE + ks * 64 + quad * 16);
            bf16x8 a1 = *(const bf16x8*)(hidb + (16 + nrow) * HSTRIDE + ks * 64 + quad * 16);
#pragma unroll
            for (int nt = 0; nt < 4; nt++) {
                acc2[0][nt] = MFMA16(a0, wf2[nt][ks], acc2[0][nt]);
                acc2[1][nt] = MFMA16(a1, wf2[nt][ks], acc2[1][nt]);
            }
        }
#pragma unroll
        for (int mt = 0; mt < 2; mt++)
#pragma unroll
            for (int nt = 0; nt < 4; nt++)
#pragma unroll
                for (int rg = 0; rg < 4; rg++) {
                    int rm = mt * 16 + quad * 4 + rg;
                    *(float*)(slab + rm * MSTRIDE + (nt * 16 + nrow) * 4) = acc2[mt][nt][rg];
                }
        {
            int e32 = ebase + w * 32;
            int dmy = dst_s[min(e32 + (lane & 31), E - 1)];
            int limit = min(32, E - e32);
            int nx = __shfl_down(dmy, 1);
            bool tl = ((lane & 31) == 31) || (dmy != nx);
            unsigned long long tm = __ballot(tl);
            float run = 0.f;
#pragma unroll
            for (int i = 0; i < 32; i++) {
                if (i < limit) {
                    run += *(const float*)(slab + i * MSTRIDE + lane * 4);
                    if (((tm >> i) & 1ull) || (i + 1 == limit)) {
                        int di = __shfl(dmy, i);
                        unsafeAtomicAdd(&agg[(size_t)di * 64 + lane], run);
                        run = 0.f;
                    }
                }
            }
        }
    }
}

// ---------------------------------------------------------------------------
// head kernel: r4 slab structure, GEMM1 swapped + cvt_pk epilogue.
// (byte-identical to r11/r14 verified best)
// ---------------------------------------------------------------------------
__global__ __launch_bounds__(256) void head_mfma(
    const ushort* __restrict__ hb, const int* __restrict__ src,
    const int* __restrict__ dst, const float* __restrict__ ea,
    const ushort* __restrict__ Wh1, const ushort* __restrict__ Wh2b,
    const float* __restrict__ hb2p,
    float* __restrict__ out, int E, int nchunks) {
    __shared__ char lds[4 * SLABSZ + 4 * HIDSZ];
    int tid = threadIdx.x;
    int w = tid >> 6, lane = tid & 63;
    int quad = lane >> 4, nrow = lane & 15;
    char* slab = lds + w * SLABSZ;
    char* hidb = lds + 4 * SLABSZ + w * HIDSZ;

    bf16x8 wf1[4][5], wh2[2];
#pragma unroll
    for (int nt = 0; nt < 4; nt++) {
        int n = nt * 16 + nrow;
#pragma unroll
        for (int ks = 0; ks < 5; ks++)
            wf1[nt][ks] = *(const bf16x8*)(Wh1 + n * 160 + ks * 32 + quad * 8);
    }
#pragma unroll
    for (int ks = 0; ks < 2; ks++)
        wh2[ks] = *(const bf16x8*)(Wh2b + nrow * 64 + ks * 32 + quad * 8);
    float hb2 = hb2p[0];

    for (int chunk = blockIdx.x; chunk < nchunks; chunk += gridDim.x) {
        int ebase = chunk * CHUNK;
        {
            int el = tid >> 1, half = tid & 1;
            int r = el & 31;
            int ec = min(ebase + el, E - 1);
            int node = half ? dst[ec] : src[ec];
            const float4* hrow = (const float4*)(hb + (size_t)node * 64);
            float4* xw = (float4*)(slab + r * XSTRIDE + half * 128);
#pragma unroll
            for (int i = 0; i < 8; i++) xw[i] = hrow[i];
            if (half == 0) {
                float4 e4 = ((const float4*)ea)[ec];
                ushort4 eb;
                eb.x = f2bf(e4.x); eb.y = f2bf(e4.y); eb.z = f2bf(e4.z); eb.w = f2bf(e4.w);
                *(ushort4*)(slab + r * XSTRIDE + 256) = eb;
            } else {
                uint2 ones2 = {0x3F803F80u, 0u};
                float4 z4 = {0.f, 0.f, 0.f, 0.f};
                *(uint2*)(slab + r * XSTRIDE + 264) = ones2;
                *(float4*)(slab + r * XSTRIDE + 272) = z4;
                *(float4*)(slab + r * XSTRIDE + 288) = z4;
                *(float4*)(slab + r * XSTRIDE + 304) = z4;
            }
        }
        f32x4 acc1[4][2];
#pragma unroll
        for (int nt = 0; nt < 4; nt++) {
            f32x4 z4;
            z4[0] = z4[1] = z4[2] = z4[3] = 0.f;
            acc1[nt][0] = z4;
            acc1[nt][1] = z4;
        }
#pragma unroll
        for (int ks = 0; ks < 5; ks++) {
            bf16x8 xb0 = *(const bf16x8*)(slab + nrow * XSTRIDE + ks * 64 + quad * 16);
            bf16x8 xb1 = *(const bf16x8*)(slab + (16 + nrow) * XSTRIDE + ks * 64 + quad * 16);
#pragma unroll
            for (int nt = 0; nt < 4; nt++) {
                acc1[nt][0] = MFMA16(wf1[nt][ks], xb0, acc1[nt][0]);
                acc1[nt][1] = MFMA16(wf1[nt][ks], xb1, acc1[nt][1]);
            }
        }
#pragma unroll
        for (int nt = 0; nt < 4; nt++)
#pragma unroll
            for (int et = 0; et < 2; et++) {
                f32x4 a = acc1[nt][et];
                float v0 = a[0] * fast_sig(a[0]);
                float v1 = a[1] * fast_sig(a[1]);
                float v2 = a[2] * fast_sig(a[2]);
                float v3 = a[3] * fast_sig(a[3]);
                int er = et * 16 + nrow;
                uint2 pk;
                pk.x = pkbf2(v0, v1);
                pk.y = pkbf2(v2, v3);
                *(uint2*)(hidb + er * HSTRIDE + nt * 32 + quad * 8) = pk;
            }
        f32x4 acc3[2];
#pragma unroll
        for (int mt = 0; mt < 2; mt++) {
            f32x4 v;
            v[0] = v[1] = v[2] = v[3] = 0.f;
            acc3[mt] = v;
        }
#pragma unroll
        for (int ks = 0; ks < 2; ks++) {
            bf16x8 a0 = *(const bf16x8*)(hidb + nrow * HSTRIDE + ks * 64 + quad * 16);
            bf16x8 a1 = *(const bf16x8*)(hidb + (16 + nrow) * HSTRIDE + ks * 64 + quad * 16);
            acc3[0] = MFMA16(a0, wh2[ks], acc3[0]);
            acc3[1] = MFMA16(a1, wh2[ks], acc3[1]);
        }
        if (nrow == 0) {
#pragma unroll
            for (int mt = 0; mt < 2; mt++)
#pragma unroll
                for (int rg = 0; rg < 4; rg++) {
                    int e = ebase + w * 32 + mt * 16 + quad * 4 + rg;
                    if (e < E) out[e] = fast_sig(acc3[mt][rg] + hb2);
                }
        }
    }
}

// ---------------------------------------------------------------------------
// GRU MFMA kernel v2: 64 nodes/block (4 waves x 16 nodes, 1 M-tile/wave).
// Grid 782 = 3.05 blocks/CU (LDS cap 3) vs old 391 = 1.5 -> 2x wave supply.
// Zeroes agg after use (replaces the per-layer memset).
// ---------------------------------------------------------------------------
__device__ __forceinline__ bf16x8 aggfrag(const float* __restrict__ row, int off) {
    float4 f0 = *(const float4*)(row + off);
    float4 f1 = *(const float4*)(row + off + 4);
    bf16x8 r;
    r[0] = (short)f2bf(f0.x); r[1] = (short)f2bf(f0.y);
    r[2] = (short)f2bf(f0.z); r[3] = (short)f2bf(f0.w);
    r[4] = (short)f2bf(f1.x); r[5] = (short)f2bf(f1.y);
    r[6] = (short)f2bf(f1.z); r[7] = (short)f2bf(f1.w);
    return r;
}

__global__ __launch_bounds__(256) void gru_mfma(
    float* __restrict__ h, ushort* __restrict__ hb, float* __restrict__ agg,
    const ushort* __restrict__ Wrzg, const ushort* __restrict__ Wnig,
    const ushort* __restrict__ Wnhg,
    const float* __restrict__ bih, const float* __restrict__ bhh, int N) {
    __shared__ char lds[128 * WRZST + 2 * 64 * WNST];  // 51200 B -> 3 blocks/CU
    int tid = threadIdx.x, w = tid >> 6, lane = tid & 63;
    int quad = lane >> 4, nrow = lane & 15;
    char* wrz = lds;
    char* wni = lds + 128 * WRZST;
    char* wnh = wni + 64 * WNST;

    {
        int r = tid >> 1, half = tid & 1;
        const uint4* g = (const uint4*)(Wrzg + r * 128 + half * 64);
        uint4* d = (uint4*)(wrz + r * WRZST + half * 128);
#pragma unroll
        for (int i = 0; i < 8; i++) d[i] = g[i];
        if (tid < 128) {
            const uint4* g2 = (const uint4*)(Wnig + (tid >> 1) * 64 + (tid & 1) * 32);
            uint4* d2 = (uint4*)(wni + (tid >> 1) * WNST + (tid & 1) * 64);
#pragma unroll
            for (int i = 0; i < 4; i++) d2[i] = g2[i];
        } else {
            int t2 = tid - 128;
            const uint4* g2 = (const uint4*)(Wnhg + (t2 >> 1) * 64 + (t2 & 1) * 32);
            uint4* d2 = (uint4*)(wnh + (t2 >> 1) * WNST + (t2 & 1) * 64);
#pragma unroll
            for (int i = 0; i < 4; i++) d2[i] = g2[i];
        }
    }
    __syncthreads();

    int nb0 = blockIdx.x * 64 + w * 16;
    if (nb0 >= N) return;

    float brz[8], bi[4], bhv[4];
#pragma unroll
    for (int nt = 0; nt < 8; nt++) brz[nt] = bih[nt * 16 + nrow] + bhh[nt * 16 + nrow];
#pragma unroll
    for (int nt = 0; nt < 4; nt++) {
        bi[nt] = bih[128 + nt * 16 + nrow];
        bhv[nt] = bhh[128 + nt * 16 + nrow];
    }

    int n0 = min(nb0 + nrow, N - 1);
    const float* ag0 = agg + (size_t)n0 * 64;
    const ushort* hb0 = hb + (size_t)n0 * 64;

    f32x4 accrz[8], acci[4], acch[4];
#pragma unroll
    for (int nt = 0; nt < 8; nt++) {
        f32x4 v; v[0] = v[1] = v[2] = v[3] = brz[nt];
        accrz[nt] = v;
    }
#pragma unroll
    for (int nt = 0; nt < 4; nt++) {
        f32x4 vi; vi[0] = vi[1] = vi[2] = vi[3] = bi[nt];
        acci[nt] = vi;
        f32x4 vh; vh[0] = vh[1] = vh[2] = vh[3] = bhv[nt];
        acch[nt] = vh;
    }

#pragma unroll
    for (int ks = 0; ks < 4; ks++) {
        bf16x8 a0;
        if (ks < 2) {
            a0 = aggfrag(ag0, ks * 32 + quad * 8);
        } else {
            a0 = *(const bf16x8*)(hb0 + (ks - 2) * 32 + quad * 8);
        }
#pragma unroll
        for (int nt = 0; nt < 8; nt++) {
            bf16x8 b = *(const bf16x8*)(wrz + (nt * 16 + nrow) * WRZST + ks * 64 + quad * 16);
            accrz[nt] = MFMA16(a0, b, accrz[nt]);
        }
        if (ks < 2) {
#pragma unroll
            for (int nt = 0; nt < 4; nt++) {
                bf16x8 b = *(const bf16x8*)(wni + (nt * 16 + nrow) * WNST + ks * 64 + quad * 16);
                acci[nt] = MFMA16(a0, b, acci[nt]);
            }
        } else {
#pragma unroll
            for (int nt = 0; nt < 4; nt++) {
                bf16x8 b = *(const bf16x8*)(wnh + (nt * 16 + nrow) * WNST + (ks - 2) * 64 + quad * 16);
                acch[nt] = MFMA16(a0, b, acch[nt]);
            }
        }
    }

    // gates + h update; zero agg for the next layer (read-before-write is
    // guaranteed: all agg loads complete before their MFMA consumers, which
    // precede these stores in program order).
#pragma unroll
    for (int nt = 0; nt < 4; nt++)
#pragma unroll
        for (int rg = 0; rg < 4; rg++) {
            int node = nb0 + quad * 4 + rg;
            if (node < N) {
                int col = nt * 16 + nrow;
                float r = fast_sig(accrz[nt][rg]);
                float z = fast_sig(accrz[nt + 4][rg]);
                float nn = fast_tanh(acci[nt][rg] + r * acch[nt][rg]);
                size_t idx = (size_t)node * 64 + col;
                float ho = h[idx];
                float hnew = (1.f - z) * nn + z * ho;
                h[idx] = hnew;
                hb[idx] = f2bf(hnew);
                agg[idx] = 0.f;
            }
        }
}

extern "C" void kernel_launch(void* const* d_in, const int* in_sizes, int n_in,
                              void* d_out, int out_size, void* d_ws, size_t ws_size,
                              hipStream_t stream) {
    const int* edge_index = (const int*)d_in[0];
    int E = in_sizes[0] / 2;
    const int* src = edge_index;
    const int* dst = edge_index + E;
    const int* kinds = (const int*)d_in[1];
    int N = in_sizes[1];
    const float* edge_attr = (const float*)d_in[2];
    const float* emb = (const float*)d_in[3];
    const float* msg_w1 = (const float*)d_in[4];
    const float* msg_b1 = (const float*)d_in[5];
    const float* msg_w2 = (const float*)d_in[6];
    const float* msg_b2 = (const float*)d_in[7];
    const float* gru_wih = (const float*)d_in[8];
    const float* gru_whh = (const float*)d_in[9];
    const float* gru_bih = (const float*)d_in[10];
    const float* gru_bhh = (const float*)d_in[11];
    const float* head_w1 = (const float*)d_in[12];
    const float* head_b1 = (const float*)d_in[13];
    const float* head_w2 = (const float*)d_in[14];
    const float* head_b2 = (const float*)d_in[15];
    float* out = (float*)d_out;

    // workspace carve-up
    char* p = (char*)d_ws;
    float* h = (float*)p;        p += (size_t)N * 64 * 4;
    float* agg = (float*)p;      p += (size_t)N * 64 * 4;
    int* deg = (int*)p;          p += (size_t)N * 4;
    int* cursor = (int*)p;       p += (size_t)N * 4;
    int* src_s = (int*)p;        p += (size_t)E * 4;
    int* dst_s = (int*)p;        p += (size_t)E * 4;
    ushort* hb = (ushort*)p;     p += (size_t)N * 64 * 2;
    ushort* Wb1 = (ushort*)p;    p += 30720 * 2;
    ushort* Wb2 = (ushort*)p;    p += 12288 * 2;
    ushort* Wh1 = (ushort*)p;    p += 10240 * 2;
    ushort* Wh2b = (ushort*)p;   p += 1024 * 2;
    ushort* Wrz = (ushort*)p;    p += 49152 * 2;
    ushort* Wni = (ushort*)p;    p += 12288 * 2;
    ushort* Wnh = (ushort*)p;    p += 12288 * 2;
    ushort* ea_sb = (ushort*)p;  p += (size_t)E * 4 * 2;

    int nchunks = (E + CHUNK - 1) / CHUNK;

    prep_kernel<<<500, 256, 0, stream>>>(msg_w1, msg_b1, msg_w2, gru_wih, gru_whh,
                                         head_w1, head_b1, head_w2,
                                         Wb1, Wb2, Wh1, Wh2b, Wrz, Wni, Wnh);
    embed_kernel<<<(N * 64 + 255) / 256, 256, 0, stream>>>(h, hb, emb, kinds, N);

    hipMemsetAsync(deg, 0, (size_t)N * sizeof(int), stream);
    hipMemsetAsync(agg, 0, (size_t)N * 64 * sizeof(float), stream);  // first-run init
    hist_kernel<<<(E + 255) / 256, 256, 0, stream>>>(dst, deg, E);
    scan_kernel<<<1, 1024, 0, stream>>>(deg, cursor, N);
    scatter_kernel<<<(E + 255) / 256, 256, 0, stream>>>(src, dst, edge_attr, cursor,
                                                        src_s, dst_s, ea_sb, E);

    for (int l = 0; l < 3; l++) {
        edge_msg_mfma<<<512, 256, 0, stream>>>(
            hb, src_s, dst_s, ea_sb,
            Wb1 + l * 10240, Wb2 + l * 4096,
            msg_b2 + l * 64, agg, E, nchunks);
        gru_mfma<<<(N + 63) / 64, 256, 0, stream>>>(
            h, hb, agg, Wrz + l * 16384, Wni + l * 4096, Wnh + l * 4096,
            gru_bih + l * 192, gru_bhh + l * 192, N);
    }
    head_mfma<<<512, 256, 0, stream>>>(hb, src, dst, edge_attr, Wh1, Wh2b,
                                       head_b2, out, E, nchunks);
}